// Round 8
// baseline (90.382 us; speedup 1.0000x reference)
//
#include <hip/hip_runtime.h>

#define C_IN 64
#define C_OUT 8
#define IMG 128
#define HW (IMG * IMG)
#define BATCH 32
#define K_STEPS 8
#define BLK_PER_B 8
#define NT 1024
#define CHUNK (HW / BLK_PER_B)                 // 2048 pixels per block
#define NREC ((K_STEPS - 1) * BATCH * BLK_PER_B)  // 1792 sync records

// ---------------------------------------------------------------------------
// Tiny pre-kernel: zero the flag words every launch (stream-ordered before the
// fused kernel). Makes graph replays and the 0xAA ws-poison trivially safe.
// ---------------------------------------------------------------------------
__global__ __launch_bounds__(256) void zero_flags_kernel(
    unsigned long long* __restrict__ flags)
{
    const int i = blockIdx.x * 256 + threadIdx.x;
    if (i < NREC) flags[i] = 0ULL;
}

// ---------------------------------------------------------------------------
// Fused kernel: 1x1 conv (+gate/bias/coords) computed in registers, then the
// 7-step stick-breaking loop. 8 blocks per batch, 2 adjacent pixels/thread.
//
// Cross-block argmax per step:
//   - every thread block-reduces to the block winner (val, idx)
//   - the owning thread writes the winner's 8-float feature to LDS
//   - lane0 of wave0 copies it to the payload slot, then RELEASE-stores the
//     packed (val_bits<<32)|(idx+1) flag word (one fence per step)
//   - wave0 lanes 0..7 RELAXED-poll the 8 flag words (cheap, r7-proven),
//     shuffle-reduce winner block, ONE acquire fence, read winner payload
//   - feat never touches global memory; the seed feature rides the payload.
//
// Deadlock-free: __launch_bounds__(1024) => VGPR<=128 => >=1 block/CU =>
// all 256 blocks resident. Slots are write-once per launch, zeroed upfront.
// Conv fma order identical to the validated semiconv; argmax/alpha/log1p
// math bitwise identical to the validated r5-r7 path.
// ---------------------------------------------------------------------------
__global__ __launch_bounds__(NT) void fused_stick_kernel(
    const float* __restrict__ x,           // [B][C_IN][HW]
    const float* __restrict__ w,           // [C_OUT][C_IN]
    const float* __restrict__ bias,        // [C_OUT]
    const float* __restrict__ gate_p,      // scalar
    const float* __restrict__ rand_pixel,  // [B][HW]
    const float* __restrict__ log_sigma_p, // scalar
    float* __restrict__ masks,             // [B][K][HW]
    float* __restrict__ scopes,            // [B][K][HW]
    unsigned long long* __restrict__ flags,// [K-1][B][BLK_PER_B]
    float* __restrict__ featpay)           // [K-1][B][BLK_PER_B][8]
{
    // batch b's 8 blocks are blockIdx = b, b+32, ... -> all on XCD b%8.
    const int b    = blockIdx.x & 31;
    const int blk  = blockIdx.x >> 5;
    const int tid  = threadIdx.x;
    const int lane = tid & 63;
    const int wid  = tid >> 6;             // 0..15

    __shared__ float swt[C_IN][C_OUT];     // transposed weights [c][o]
    __shared__ float swv[2][16];
    __shared__ int   swi[2][16];
    __shared__ float sCand[2][C_OUT];
    __shared__ float sSeedF[2][C_OUT];

    if (tid < C_IN * C_OUT) swt[tid & (C_IN - 1)][tid >> 6] = w[tid];
    __syncthreads();

    const float gate      = *gate_p;
    const float inv_sigma = expf(-(*log_sigma_p));

    const float* xb = x + (size_t)b * C_IN * HW;
    const float* rb = rand_pixel + (size_t)b * HW;
    float* mb = masks  + (size_t)b * (K_STEPS * HW);
    float* sb = scopes + (size_t)b * (K_STEPS * HW);

    const int p0 = blk * CHUNK + 2 * tid;  // own pixels p0, p0+1 (adjacent)

    // ---- fused 1x1 conv: 2 pixels x 8 channels in registers ----
    float f0[C_OUT], f1[C_OUT];
    #pragma unroll
    for (int o = 0; o < C_OUT; ++o) { const float bv = bias[o]; f0[o] = bv; f1[o] = bv; }

    for (int c = 0; c < C_IN; ++c) {
        const float2 xv = *(const float2*)(xb + (size_t)c * HW + p0);
        #pragma unroll
        for (int o = 0; o < C_OUT; ++o) {
            const float wv = swt[c][o];
            f0[o] = fmaf(wv, xv.x, f0[o]);
            f1[o] = fmaf(wv, xv.y, f1[o]);
        }
    }

    const float stepc = 2.0f / (IMG - 1);
    #pragma unroll
    for (int o = 0; o < 6; ++o) { f0[o] *= gate; f1[o] *= gate; }
    f0[6] = fmaf(gate, f0[6], -1.0f + stepc * (float)(p0 >> 7));
    f1[6] = fmaf(gate, f1[6], -1.0f + stepc * (float)((p0 + 1) >> 7));
    f0[7] = fmaf(gate, f0[7], -1.0f + stepc * (float)(p0 & 127));
    f1[7] = fmaf(gate, f1[7], -1.0f + stepc * (float)((p0 + 1) & 127));

    const float2 rr = *(const float2*)(rb + p0);
    float rp0 = rr.x, rp1 = rr.y;
    float ls0 = 0.0f, ls1 = 0.0f;
    *(float2*)(sb + p0) = make_float2(0.0f, 0.0f);   // log_scopes[:,0] = 0

    for (int s = 0; s < K_STEPS - 1; ++s) {
        const int par = s & 1;

        // ---- per-thread argmax of rand * exp(log_scope); first occurrence ----
        float bv; int bi;
        {
            const float v0 = rp0 * expf(ls0);
            const float v1 = rp1 * expf(ls1);
            bv = v0; bi = p0;
            if (v1 > bv) { bv = v1; bi = p0 + 1; }   // strict > keeps lower idx
        }
        #pragma unroll
        for (int off = 1; off < 64; off <<= 1) {
            const float ov = __shfl_xor(bv, off);
            const int   oi = __shfl_xor(bi, off);
            if (ov > bv || (ov == bv && oi < bi)) { bv = ov; bi = oi; }
        }
        if (lane == 0) { swv[par][wid] = bv; swi[par][wid] = bi; }
        __syncthreads();

        // ---- every thread block-reduces the 16 wave partials ----
        float cv = swv[par][0];
        int   ci = swi[par][0];
        #pragma unroll
        for (int t = 1; t < 16; ++t) {
            const float vv = swv[par][t];
            const int   ii = swi[par][t];
            if (vv > cv || (vv == cv && ii < ci)) { cv = vv; ci = ii; }
        }
        // owner thread deposits the block candidate's feature vector
        if (ci == p0) {
            #pragma unroll
            for (int o = 0; o < C_OUT; ++o) sCand[par][o] = f0[o];
        } else if (ci == p0 + 1) {
            #pragma unroll
            for (int o = 0; o < C_OUT; ++o) sCand[par][o] = f1[o];
        }
        __syncthreads();

        // ---- wave 0: publish (payload then release-flag), poll, fetch seed ----
        if (wid == 0) {
            const int recbase = (s * BATCH + b) * BLK_PER_B;
            if (lane == 0) {
                float* pay = featpay + (size_t)(recbase + blk) * C_OUT;
                *(float4*)(pay)     = make_float4(sCand[par][0], sCand[par][1],
                                                  sCand[par][2], sCand[par][3]);
                *(float4*)(pay + 4) = make_float4(sCand[par][4], sCand[par][5],
                                                  sCand[par][6], sCand[par][7]);
                const unsigned long long pk =
                    ((unsigned long long)__float_as_uint(cv) << 32) |
                    (unsigned long long)(unsigned int)(ci + 1);
                __hip_atomic_store(&flags[recbase + blk], pk,
                                   __ATOMIC_RELEASE, __HIP_MEMORY_SCOPE_AGENT);
            }
            float gv = -1.0f; int gi = 0x7fffffff; int gb = 0;
            if (lane < BLK_PER_B) {
                unsigned long long got;
                do {
                    got = __hip_atomic_load(&flags[recbase + lane],
                                            __ATOMIC_RELAXED,
                                            __HIP_MEMORY_SCOPE_AGENT);
                } while (got == 0ULL);
                gv = __uint_as_float((unsigned int)(got >> 32));
                gi = (int)(unsigned int)(got & 0xffffffffULL) - 1;
                gb = lane;
            }
            #pragma unroll
            for (int off = 1; off < 8; off <<= 1) {
                const float ov = __shfl_xor(gv, off);
                const int   oi = __shfl_xor(gi, off);
                const int   ob = __shfl_xor(gb, off);
                if (ov > gv || (ov == gv && oi < gi)) { gv = ov; gi = oi; gb = ob; }
            }
            __builtin_amdgcn_fence(__ATOMIC_ACQUIRE, "agent");
            if (lane < C_OUT) {
                sSeedF[par][lane] = featpay[(size_t)(recbase + gb) * C_OUT + lane];
            }
        }
        __syncthreads();

        // ---- distances vs seed feature, alpha, mask/scope update ----
        float sq0 = 0.0f, sq1 = 0.0f;
        #pragma unroll
        for (int o = 0; o < C_OUT; ++o) {
            const float sv = sSeedF[par][o];
            const float d0 = f0[o] - sv; sq0 += d0 * d0;
            const float d1 = f1[o] - sv; sq1 += d1 * d1;
        }
        float m0, m1;
        {
            const float t = sq0 * inv_sigma;
            float alpha = expf(-t);
            float log_a;
            if (alpha >= 0.99f)      { alpha = 0.99f; log_a = -0.010050336f; }
            else if (alpha <= 0.01f) { alpha = 0.01f; log_a = -4.6051702f;  }
            else                     { log_a = -t; }
            m0 = ls0 + log_a;
            ls0 += log1pf(-alpha);
        }
        {
            const float t = sq1 * inv_sigma;
            float alpha = expf(-t);
            float log_a;
            if (alpha >= 0.99f)      { alpha = 0.99f; log_a = -0.010050336f; }
            else if (alpha <= 0.01f) { alpha = 0.01f; log_a = -4.6051702f;  }
            else                     { log_a = -t; }
            m1 = ls1 + log_a;
            ls1 += log1pf(-alpha);
        }
        *(float2*)(mb + s * HW + p0)       = make_float2(m0, m1);
        *(float2*)(sb + (s + 1) * HW + p0) = make_float2(ls0, ls1);
        // LDS safety: all [par] slots are re-written only two steps later,
        // with >=2 barriers in between.
    }

    *(float2*)(mb + (K_STEPS - 1) * HW + p0) = make_float2(ls0, ls1);
}

extern "C" void kernel_launch(void* const* d_in, const int* in_sizes, int n_in,
                              void* d_out, int out_size, void* d_ws, size_t ws_size,
                              hipStream_t stream) {
    const float* x          = (const float*)d_in[0];  // [32,64,128,128]
    const float* rand_pixel = (const float*)d_in[1];  // [32,1,128,128]
    const float* conv_w     = (const float*)d_in[2];  // [8,64]
    const float* conv_b     = (const float*)d_in[3];  // [8]
    const float* gate       = (const float*)d_in[4];  // scalar
    const float* log_sigma  = (const float*)d_in[5];  // scalar

    float* masks  = (float*)d_out;                          // [32,8,128,128]
    float* scopes = masks + (long long)BATCH * K_STEPS * HW;

    unsigned long long* flags = (unsigned long long*)d_ws;      // 14336 B
    float* featpay = (float*)((char*)d_ws + (size_t)NREC * 8);  // 57344 B

    zero_flags_kernel<<<(NREC + 255) / 256, 256, 0, stream>>>(flags);

    fused_stick_kernel<<<BATCH * BLK_PER_B, NT, 0, stream>>>(
        x, conv_w, conv_b, gate, rand_pixel, log_sigma,
        masks, scopes, flags, featpay);
}

// Round 9
// 77.799 us; speedup vs baseline: 1.1617x; 1.1617x over previous
//
#include <hip/hip_runtime.h>

#define C_IN 64
#define C_OUT 8
#define IMG 128
#define HW (IMG * IMG)
#define BATCH 32
#define K_STEPS 8

#define FEAT_BYTES ((size_t)BATCH * HW * C_OUT * 4)   // 16,777,216
#define BLK_PER_B 8
#define NFLAGS ((K_STEPS - 1) * BATCH * BLK_PER_B)    // 1792 u64 words

// ---------------------------------------------------------------------------
// Kernel A (proven r7): 1x1 conv + gate + bias + coordinate channels.
// feat layout: [B][HW][C_OUT] (pixel-major, 32B per pixel) in workspace.
// Block 0 zeroes the cross-block sync flags (stream-ordered; replay-safe).
// ---------------------------------------------------------------------------
__global__ __launch_bounds__(256) void semiconv_kernel(
    const float* __restrict__ x,      // [B][C_IN][HW]
    const float* __restrict__ w,      // [C_OUT][C_IN]
    const float* __restrict__ bias,   // [C_OUT]
    const float* __restrict__ gate_p, // scalar
    float* __restrict__ feat,         // [B][HW][C_OUT]
    unsigned long long* __restrict__ flags)
{
    __shared__ float sw[C_OUT * C_IN];
    const int tid = threadIdx.x;
    if (blockIdx.x == 0) {
        for (int k = tid; k < NFLAGS; k += 256) flags[k] = 0ULL;
    }
    for (int i = tid; i < C_OUT * C_IN; i += 256) sw[i] = w[i];
    __syncthreads();

    const int b  = blockIdx.x >> 4;
    const int p4 = (((blockIdx.x & 15) * 256) + tid) * 4;

    const float gate = *gate_p;
    const float* xb = x + (long long)b * C_IN * HW + p4;

    float acc[C_OUT][4];
    #pragma unroll
    for (int o = 0; o < C_OUT; ++o) {
        const float bv = bias[o];
        #pragma unroll
        for (int j = 0; j < 4; ++j) acc[o][j] = bv;
    }

    for (int c = 0; c < C_IN; ++c) {
        const float4 xv = *(const float4*)(xb + c * HW);
        const float xs[4] = {xv.x, xv.y, xv.z, xv.w};
        #pragma unroll
        for (int o = 0; o < C_OUT; ++o) {
            const float wv = sw[o * C_IN + c];
            #pragma unroll
            for (int j = 0; j < 4; ++j) acc[o][j] = fmaf(wv, xs[j], acc[o][j]);
        }
    }

    const int row  = p4 / IMG;
    const int col0 = p4 % IMG;
    const float step = 2.0f / (IMG - 1);
    const float g1 = -1.0f + step * (float)row;

    float* dst = feat + ((long long)b * HW + p4) * C_OUT;
    #pragma unroll
    for (int j = 0; j < 4; ++j) {
        float o0 = gate * acc[0][j];
        float o1 = gate * acc[1][j];
        float o2 = gate * acc[2][j];
        float o3 = gate * acc[3][j];
        float o4 = gate * acc[4][j];
        float o5 = gate * acc[5][j];
        float o6 = gate * acc[6][j] + g1;
        float o7 = gate * acc[7][j] + (-1.0f + step * (float)(col0 + j));
        *(float4*)(dst + j * C_OUT)     = make_float4(o0, o1, o2, o3);
        *(float4*)(dst + j * C_OUT + 4) = make_float4(o4, o5, o6, o7);
    }
}

// ---------------------------------------------------------------------------
// Kernel B: stick-breaking, 8 blocks per batch (grid 256 = 1 block/CU).
// ONE barrier per step; every wave polls and wakes independently:
//   argmax partials -> LDS -> barrier -> each wave shuffle-reduces the 16
//   partials itself -> wave0.lane0 publishes packed (val,idx+1) RELAXED ->
//   each wave's lanes 0..7 RELAXED-poll the 8 flag words, 3-round butterfly,
//   lane0 broadcast -> uniform seed load from feat -> compute.
// Single-barrier parity safety: wave A re-writes partials[par] at step s+2
// only after passing barrier(s+1), which requires every wave B to have
// finished its step-s reads of partials[par]. Flags are per-step write-once,
// zeroed each launch by kernel A (stream-ordered) => replay-safe.
// Deadlock-free: grid 256 with 1024-thread blocks => 1 block/CU, all resident.
// argmax / alpha / log1pf math bitwise identical to the validated r5-r7 path.
// ---------------------------------------------------------------------------
#define NT 1024
#define CHUNK (HW / BLK_PER_B)   // 2048
// each thread owns adjacent pixels p0, p0+1

__global__ __launch_bounds__(NT) void stick_kernel(
    const float* __restrict__ feat,        // [B][HW][C_OUT]
    const float* __restrict__ rand_pixel,  // [B][HW]
    const float* __restrict__ log_sigma_p, // scalar
    float* __restrict__ masks,             // [B][K][HW]
    float* __restrict__ scopes,            // [B][K][HW]
    unsigned long long* __restrict__ flags)// [K-1][B][BLK_PER_B]
{
    // batch b's 8 blocks share blockIdx%8 -> same XCD (L2-local flags).
    const int b    = blockIdx.x & 31;
    const int blk  = blockIdx.x >> 5;
    const int tid  = threadIdx.x;
    const int lane = tid & 63;
    const int wid  = tid >> 6;             // 0..15

    const float inv_sigma = expf(-(*log_sigma_p));

    const float* fb = feat + (size_t)b * HW * C_OUT;
    const float* rb = rand_pixel + (size_t)b * HW;
    float* mb = masks  + (size_t)b * (K_STEPS * HW);
    float* sb = scopes + (size_t)b * (K_STEPS * HW);

    const int p0 = blk * CHUNK + 2 * tid;  // adjacent pixels p0, p0+1

    // own features: 64 contiguous bytes per thread
    const float4 f0a = *(const float4*)(fb + (size_t)p0 * C_OUT);
    const float4 f0b = *(const float4*)(fb + (size_t)p0 * C_OUT + 4);
    const float4 f1a = *(const float4*)(fb + (size_t)p0 * C_OUT + 8);
    const float4 f1b = *(const float4*)(fb + (size_t)p0 * C_OUT + 12);

    const float2 rr = *(const float2*)(rb + p0);
    float ls0 = 0.0f, ls1 = 0.0f;
    *(float2*)(sb + p0) = make_float2(0.0f, 0.0f);   // log_scopes[:,0] = 0

    __shared__ float swv[2][16];
    __shared__ int   swi[2][16];

    for (int s = 0; s < K_STEPS - 1; ++s) {
        const int par = s & 1;
        const int recbase = (s * BATCH + b) * BLK_PER_B;

        // ---- per-thread argmax of rand * exp(log_scope); first occurrence ----
        float bv; int bi;
        {
            const float v0 = rr.x * expf(ls0);
            const float v1 = rr.y * expf(ls1);
            bv = v0; bi = p0;
            if (v1 > bv) { bv = v1; bi = p0 + 1; }   // strict > keeps lower idx
        }
        // ---- xor-butterfly wave reduce (max, tie -> min idx) ----
        #pragma unroll
        for (int off = 1; off < 64; off <<= 1) {
            const float ov = __shfl_xor(bv, off);
            const int   oi = __shfl_xor(bi, off);
            if (ov > bv || (ov == bv && oi < bi)) { bv = ov; bi = oi; }
        }
        if (lane == 0) { swv[par][wid] = bv; swi[par][wid] = bi; }
        __syncthreads();   // the ONLY barrier this step

        // ---- every wave: shuffle-reduce the 16 wave partials ----
        float cv = (lane < 16) ? swv[par][lane] : -1.0f;
        int   ci = (lane < 16) ? swi[par][lane] : 0x7fffffff;
        #pragma unroll
        for (int off = 1; off < 16; off <<= 1) {
            const float ov = __shfl_xor(cv, off);
            const int   oi = __shfl_xor(ci, off);
            if (ov > cv || (ov == cv && oi < ci)) { cv = ov; ci = oi; }
        }
        // ---- wave0.lane0 publishes the block winner (payload in the word) ----
        if (wid == 0 && lane == 0) {
            const unsigned long long pk =
                ((unsigned long long)__float_as_uint(cv) << 32) |
                (unsigned long long)(unsigned int)(ci + 1);
            __hip_atomic_store(&flags[recbase + blk], pk,
                               __ATOMIC_RELAXED, __HIP_MEMORY_SCOPE_AGENT);
        }
        // ---- every wave polls all 8 flag words; wakes independently ----
        float gv = -1.0f; int gi = 0x7fffffff;
        if (lane < BLK_PER_B) {
            unsigned long long got;
            do {
                got = __hip_atomic_load(&flags[recbase + lane],
                                        __ATOMIC_RELAXED,
                                        __HIP_MEMORY_SCOPE_AGENT);
            } while (got == 0ULL);
            gv = __uint_as_float((unsigned int)(got >> 32));
            gi = (int)(unsigned int)(got & 0xffffffffULL) - 1;
        }
        #pragma unroll
        for (int off = 1; off < 8; off <<= 1) {
            const float ov = __shfl_xor(gv, off);
            const int   oi = __shfl_xor(gi, off);
            if (ov > gv || (ov == gv && oi < gi)) { gv = ov; gi = oi; }
        }
        const int seedIdx = __shfl(gi, 0);

        // seed features (uniform address -> broadcast load, L2-local)
        const float4 s0 = *(const float4*)(fb + (size_t)seedIdx * C_OUT);
        const float4 s1 = *(const float4*)(fb + (size_t)seedIdx * C_OUT + 4);

        // ---- distances, alpha, mask/scope update (validated math) ----
        float sq0 = 0.0f, sq1 = 0.0f, d;
        d = f0a.x - s0.x; sq0 += d * d;
        d = f0a.y - s0.y; sq0 += d * d;
        d = f0a.z - s0.z; sq0 += d * d;
        d = f0a.w - s0.w; sq0 += d * d;
        d = f0b.x - s1.x; sq0 += d * d;
        d = f0b.y - s1.y; sq0 += d * d;
        d = f0b.z - s1.z; sq0 += d * d;
        d = f0b.w - s1.w; sq0 += d * d;
        d = f1a.x - s0.x; sq1 += d * d;
        d = f1a.y - s0.y; sq1 += d * d;
        d = f1a.z - s0.z; sq1 += d * d;
        d = f1a.w - s0.w; sq1 += d * d;
        d = f1b.x - s1.x; sq1 += d * d;
        d = f1b.y - s1.y; sq1 += d * d;
        d = f1b.z - s1.z; sq1 += d * d;
        d = f1b.w - s1.w; sq1 += d * d;

        float m0, m1;
        {
            const float t = sq0 * inv_sigma;
            float alpha = expf(-t);
            float log_a;
            if (alpha >= 0.99f)      { alpha = 0.99f; log_a = -0.010050336f; } // ln(0.99)
            else if (alpha <= 0.01f) { alpha = 0.01f; log_a = -4.6051702f;  }  // ln(0.01)
            else                     { log_a = -t; }
            m0 = ls0 + log_a;
            ls0 += log1pf(-alpha);
        }
        {
            const float t = sq1 * inv_sigma;
            float alpha = expf(-t);
            float log_a;
            if (alpha >= 0.99f)      { alpha = 0.99f; log_a = -0.010050336f; }
            else if (alpha <= 0.01f) { alpha = 0.01f; log_a = -4.6051702f;  }
            else                     { log_a = -t; }
            m1 = ls1 + log_a;
            ls1 += log1pf(-alpha);
        }
        *(float2*)(mb + s * HW + p0)       = make_float2(m0, m1);
        *(float2*)(sb + (s + 1) * HW + p0) = make_float2(ls0, ls1);
    }

    *(float2*)(mb + (K_STEPS - 1) * HW + p0) = make_float2(ls0, ls1);
}

extern "C" void kernel_launch(void* const* d_in, const int* in_sizes, int n_in,
                              void* d_out, int out_size, void* d_ws, size_t ws_size,
                              hipStream_t stream) {
    const float* x          = (const float*)d_in[0];  // [32,64,128,128]
    const float* rand_pixel = (const float*)d_in[1];  // [32,1,128,128]
    const float* conv_w     = (const float*)d_in[2];  // [8,64]
    const float* conv_b     = (const float*)d_in[3];  // [8]
    const float* gate       = (const float*)d_in[4];  // scalar
    const float* log_sigma  = (const float*)d_in[5];  // scalar

    float* masks  = (float*)d_out;                          // [32,8,128,128]
    float* scopes = masks + (long long)BATCH * K_STEPS * HW;

    float* feat = (float*)d_ws;  // 16.8 MB
    unsigned long long* flags =
        (unsigned long long*)((char*)d_ws + FEAT_BYTES);     // 14 KB

    semiconv_kernel<<<(BATCH * HW) / (256 * 4), 256, 0, stream>>>(
        x, conv_w, conv_b, gate, feat, flags);

    stick_kernel<<<BATCH * BLK_PER_B, NT, 0, stream>>>(
        feat, rand_pixel, log_sigma, masks, scopes, flags);
}

// Round 10
// 72.641 us; speedup vs baseline: 1.2442x; 1.0710x over previous
//
#include <hip/hip_runtime.h>

#define C_IN 64
#define C_OUT 8
#define IMG 128
#define HW (IMG * IMG)
#define BATCH 32
#define K_STEPS 8

#define FEAT_BYTES ((size_t)BATCH * HW * C_OUT * 4)   // 16,777,216
#define BLK_PER_B 8
#define NFLAGS ((K_STEPS - 1) * BATCH * BLK_PER_B)    // 1792 u64 words
#define NSEED0 (BATCH * 16)                           // 512 u64 words

union F2U { float2 f2; unsigned long long u; };

// ---------------------------------------------------------------------------
// Kernel A: 1x1 conv + gate + bias + coords (validated math, unchanged) PLUS
// per-block step-0 rand-argmax: block (b,blk16) writes its local (max,idx)
// packed to seed0[b*16+blk16] (plain write-once store, stream-ordered before
// kernel B => no atomics, no zeroing, replay-safe).
// Block 0 zeroes the cross-block sync flags for steps 1..6.
// ---------------------------------------------------------------------------
__global__ __launch_bounds__(256) void semiconv_kernel(
    const float* __restrict__ x,      // [B][C_IN][HW]
    const float* __restrict__ w,      // [C_OUT][C_IN]
    const float* __restrict__ bias,   // [C_OUT]
    const float* __restrict__ gate_p, // scalar
    const float* __restrict__ rand_pixel, // [B][HW]
    float* __restrict__ feat,         // [B][HW][C_OUT]
    unsigned long long* __restrict__ flags,
    unsigned long long* __restrict__ seed0)
{
    __shared__ float sw[C_OUT * C_IN];
    __shared__ float spv[4];
    __shared__ int   spi[4];
    const int tid = threadIdx.x;
    if (blockIdx.x == 0) {
        for (int k = tid; k < NFLAGS; k += 256) flags[k] = 0ULL;
    }
    for (int i = tid; i < C_OUT * C_IN; i += 256) sw[i] = w[i];
    __syncthreads();

    const int b     = blockIdx.x >> 4;
    const int blk16 = blockIdx.x & 15;
    const int p4    = ((blk16 * 256) + tid) * 4;

    const float gate = *gate_p;
    const float* xb = x + (long long)b * C_IN * HW + p4;

    float acc[C_OUT][4];
    #pragma unroll
    for (int o = 0; o < C_OUT; ++o) {
        const float bv = bias[o];
        #pragma unroll
        for (int j = 0; j < 4; ++j) acc[o][j] = bv;
    }

    for (int c = 0; c < C_IN; ++c) {
        const float4 xv = *(const float4*)(xb + c * HW);
        const float xs[4] = {xv.x, xv.y, xv.z, xv.w};
        #pragma unroll
        for (int o = 0; o < C_OUT; ++o) {
            const float wv = sw[o * C_IN + c];
            #pragma unroll
            for (int j = 0; j < 4; ++j) acc[o][j] = fmaf(wv, xs[j], acc[o][j]);
        }
    }

    const int row  = p4 / IMG;
    const int col0 = p4 % IMG;
    const float step = 2.0f / (IMG - 1);
    const float g1 = -1.0f + step * (float)row;

    float* dst = feat + ((long long)b * HW + p4) * C_OUT;
    #pragma unroll
    for (int j = 0; j < 4; ++j) {
        float o0 = gate * acc[0][j];
        float o1 = gate * acc[1][j];
        float o2 = gate * acc[2][j];
        float o3 = gate * acc[3][j];
        float o4 = gate * acc[4][j];
        float o5 = gate * acc[5][j];
        float o6 = gate * acc[6][j] + g1;
        float o7 = gate * acc[7][j] + (-1.0f + step * (float)(col0 + j));
        *(float4*)(dst + j * C_OUT)     = make_float4(o0, o1, o2, o3);
        *(float4*)(dst + j * C_OUT + 4) = make_float4(o4, o5, o6, o7);
    }

    // ---- step-0 seed candidate: argmax of rand over this block's 1024 px ----
    // value compared is raw rand == rand * expf(0): bitwise identical to the
    // stick kernel's step-0 comparison in the validated path.
    const int lane = tid & 63;
    const int wid  = tid >> 6;
    const float4 rv = *(const float4*)(rand_pixel + (size_t)b * HW + p4);
    float bv = rv.x; int bi = p4;
    if (rv.y > bv) { bv = rv.y; bi = p4 + 1; }   // ascending, strict >
    if (rv.z > bv) { bv = rv.z; bi = p4 + 2; }
    if (rv.w > bv) { bv = rv.w; bi = p4 + 3; }
    #pragma unroll
    for (int off = 1; off < 64; off <<= 1) {
        const float ov = __shfl_xor(bv, off);
        const int   oi = __shfl_xor(bi, off);
        if (ov > bv || (ov == bv && oi < bi)) { bv = ov; bi = oi; }
    }
    if (lane == 0) { spv[wid] = bv; spi[wid] = bi; }
    __syncthreads();
    if (tid == 0) {
        float v = spv[0]; int ix = spi[0];
        #pragma unroll
        for (int wv2 = 1; wv2 < 4; ++wv2) {
            if (spv[wv2] > v || (spv[wv2] == v && spi[wv2] < ix)) { v = spv[wv2]; ix = spi[wv2]; }
        }
        seed0[(b << 4) | blk16] =
            ((unsigned long long)__float_as_uint(v) << 32) |
            (unsigned long long)(unsigned int)ix;
    }
}

// ---------------------------------------------------------------------------
// Kernel B: stick-breaking, 8 blocks per batch (grid 256 = 1 block/CU).
// Step 0: seed comes from seed0[] (written by kernel A, stream-ordered) —
//         no publish, no poll, no barrier.
// Steps 1..6: EXACT r7 protocol (proven fastest): partials -> LDS -> barrier
//         -> wave0 reduces, publishes packed (val,idx+1) RELAXED, polls the
//         8 flag words, reduces, sSeed -> barrier -> everyone proceeds.
//         (15 waves park at barrier #2 while wave0 polls: parked waves don't
//          consume issue slots — r9 proved all-wave polling is worse.)
// masks/scopes stores are nontemporal (streamed, never re-read).
// Deadlock-free: grid 256, 1024-thread blocks => all blocks resident.
// argmax / alpha / log1pf math bitwise identical to the validated r5-r9 path.
// ---------------------------------------------------------------------------
#define NT 1024
#define CHUNK (HW / BLK_PER_B)   // 2048

__device__ __forceinline__ void nt_store2(float* p, float a, float bfl) {
    F2U v; v.f2 = make_float2(a, bfl);
    __builtin_nontemporal_store(v.u, (unsigned long long*)p);
}

__global__ __launch_bounds__(NT) void stick_kernel(
    const float* __restrict__ feat,        // [B][HW][C_OUT]
    const float* __restrict__ rand_pixel,  // [B][HW]
    const float* __restrict__ log_sigma_p, // scalar
    float* __restrict__ masks,             // [B][K][HW]
    float* __restrict__ scopes,            // [B][K][HW]
    unsigned long long* __restrict__ flags,// [K-1][B][BLK_PER_B]
    const unsigned long long* __restrict__ seed0) // [B][16]
{
    // batch b's 8 blocks share blockIdx%8 -> same XCD (L2-local flags).
    const int b    = blockIdx.x & 31;
    const int blk  = blockIdx.x >> 5;
    const int tid  = threadIdx.x;
    const int lane = tid & 63;
    const int wid  = tid >> 6;             // 0..15

    const float inv_sigma = expf(-(*log_sigma_p));

    const float* fb = feat + (size_t)b * HW * C_OUT;
    const float* rb = rand_pixel + (size_t)b * HW;
    float* mb = masks  + (size_t)b * (K_STEPS * HW);
    float* sb = scopes + (size_t)b * (K_STEPS * HW);

    const int p0 = blk * CHUNK + 2 * tid;  // adjacent pixels p0, p0+1

    // own features: 64 contiguous bytes per thread
    const float4 f0a = *(const float4*)(fb + (size_t)p0 * C_OUT);
    const float4 f0b = *(const float4*)(fb + (size_t)p0 * C_OUT + 4);
    const float4 f1a = *(const float4*)(fb + (size_t)p0 * C_OUT + 8);
    const float4 f1b = *(const float4*)(fb + (size_t)p0 * C_OUT + 12);

    const float2 rr = *(const float2*)(rb + p0);
    float ls0 = 0.0f, ls1 = 0.0f;
    nt_store2(sb + p0, 0.0f, 0.0f);        // log_scopes[:,0] = 0

    __shared__ float swv[2][16];
    __shared__ int   swi[2][16];
    __shared__ int   sSeed[2];

    for (int s = 0; s < K_STEPS - 1; ++s) {
        const int par = s & 1;
        int seedIdx;

        if (s == 0) {
            // ---- seed precomputed by semiconv: reduce 16 slots, no sync ----
            float gv = -1.0f; int gi = 0x7fffffff;
            if (lane < 16) {
                const unsigned long long got = seed0[(b << 4) | lane];
                gv = __uint_as_float((unsigned int)(got >> 32));
                gi = (int)(unsigned int)(got & 0xffffffffULL);
            }
            #pragma unroll
            for (int off = 1; off < 16; off <<= 1) {
                const float ov = __shfl_xor(gv, off);
                const int   oi = __shfl_xor(gi, off);
                if (ov > gv || (ov == gv && oi < gi)) { gv = ov; gi = oi; }
            }
            seedIdx = __shfl(gi, 0);
        } else {
            const int recbase = (s * BATCH + b) * BLK_PER_B;

            // ---- per-thread argmax of rand * exp(log_scope) ----
            float bv; int bi;
            {
                const float v0 = rr.x * expf(ls0);
                const float v1 = rr.y * expf(ls1);
                bv = v0; bi = p0;
                if (v1 > bv) { bv = v1; bi = p0 + 1; }  // strict > keeps lower idx
            }
            #pragma unroll
            for (int off = 1; off < 64; off <<= 1) {
                const float ov = __shfl_xor(bv, off);
                const int   oi = __shfl_xor(bi, off);
                if (ov > bv || (ov == bv && oi < bi)) { bv = ov; bi = oi; }
            }
            if (lane == 0) { swv[par][wid] = bv; swi[par][wid] = bi; }
            __syncthreads();

            // ---- wave 0: reduce, publish, poll peers, global reduce ----
            if (wid == 0) {
                float v = (lane < 16) ? swv[par][lane] : -1.0f;
                int   ix = (lane < 16) ? swi[par][lane] : 0x7fffffff;
                #pragma unroll
                for (int off = 1; off < 16; off <<= 1) {
                    const float ov = __shfl_xor(v, off);
                    const int   oi = __shfl_xor(ix, off);
                    if (ov > v || (ov == v && oi < ix)) { v = ov; ix = oi; }
                }
                if (lane == 0) {
                    const unsigned long long pk =
                        ((unsigned long long)__float_as_uint(v) << 32) |
                        (unsigned long long)(unsigned int)(ix + 1);
                    __hip_atomic_store(&flags[recbase + blk], pk,
                                       __ATOMIC_RELAXED, __HIP_MEMORY_SCOPE_AGENT);
                }
                float gv = -1.0f; int gi = 0x7fffffff;
                if (lane < BLK_PER_B) {
                    unsigned long long got;
                    do {
                        got = __hip_atomic_load(&flags[recbase + lane],
                                                __ATOMIC_RELAXED,
                                                __HIP_MEMORY_SCOPE_AGENT);
                    } while (got == 0ULL);
                    gv = __uint_as_float((unsigned int)(got >> 32));
                    gi = (int)(unsigned int)(got & 0xffffffffULL) - 1;
                }
                #pragma unroll
                for (int off = 1; off < 8; off <<= 1) {
                    const float ov = __shfl_xor(gv, off);
                    const int   oi = __shfl_xor(gi, off);
                    if (ov > gv || (ov == gv && oi < gi)) { gv = ov; gi = oi; }
                }
                if (lane == 0) sSeed[par] = gi;
            }
            __syncthreads();
            seedIdx = sSeed[par];
        }

        // seed features (uniform address -> broadcast load, L2/L3-hot)
        const float4 s0 = *(const float4*)(fb + (size_t)seedIdx * C_OUT);
        const float4 s1 = *(const float4*)(fb + (size_t)seedIdx * C_OUT + 4);

        // ---- distances, alpha, mask/scope update (validated math) ----
        float sq0 = 0.0f, sq1 = 0.0f, d;
        d = f0a.x - s0.x; sq0 += d * d;
        d = f0a.y - s0.y; sq0 += d * d;
        d = f0a.z - s0.z; sq0 += d * d;
        d = f0a.w - s0.w; sq0 += d * d;
        d = f0b.x - s1.x; sq0 += d * d;
        d = f0b.y - s1.y; sq0 += d * d;
        d = f0b.z - s1.z; sq0 += d * d;
        d = f0b.w - s1.w; sq0 += d * d;
        d = f1a.x - s0.x; sq1 += d * d;
        d = f1a.y - s0.y; sq1 += d * d;
        d = f1a.z - s0.z; sq1 += d * d;
        d = f1a.w - s0.w; sq1 += d * d;
        d = f1b.x - s1.x; sq1 += d * d;
        d = f1b.y - s1.y; sq1 += d * d;
        d = f1b.z - s1.z; sq1 += d * d;
        d = f1b.w - s1.w; sq1 += d * d;

        float m0, m1;
        {
            const float t = sq0 * inv_sigma;
            float alpha = expf(-t);
            float log_a;
            if (alpha >= 0.99f)      { alpha = 0.99f; log_a = -0.010050336f; } // ln(0.99)
            else if (alpha <= 0.01f) { alpha = 0.01f; log_a = -4.6051702f;  }  // ln(0.01)
            else                     { log_a = -t; }
            m0 = ls0 + log_a;
            ls0 += log1pf(-alpha);
        }
        {
            const float t = sq1 * inv_sigma;
            float alpha = expf(-t);
            float log_a;
            if (alpha >= 0.99f)      { alpha = 0.99f; log_a = -0.010050336f; }
            else if (alpha <= 0.01f) { alpha = 0.01f; log_a = -4.6051702f;  }
            else                     { log_a = -t; }
            m1 = ls1 + log_a;
            ls1 += log1pf(-alpha);
        }
        nt_store2(mb + s * HW + p0, m0, m1);
        nt_store2(sb + (s + 1) * HW + p0, ls0, ls1);
    }

    nt_store2(mb + (K_STEPS - 1) * HW + p0, ls0, ls1);  // last mask = final scope
}

extern "C" void kernel_launch(void* const* d_in, const int* in_sizes, int n_in,
                              void* d_out, int out_size, void* d_ws, size_t ws_size,
                              hipStream_t stream) {
    const float* x          = (const float*)d_in[0];  // [32,64,128,128]
    const float* rand_pixel = (const float*)d_in[1];  // [32,1,128,128]
    const float* conv_w     = (const float*)d_in[2];  // [8,64]
    const float* conv_b     = (const float*)d_in[3];  // [8]
    const float* gate       = (const float*)d_in[4];  // scalar
    const float* log_sigma  = (const float*)d_in[5];  // scalar

    float* masks  = (float*)d_out;                          // [32,8,128,128]
    float* scopes = masks + (long long)BATCH * K_STEPS * HW;

    float* feat = (float*)d_ws;  // 16.8 MB
    unsigned long long* flags =
        (unsigned long long*)((char*)d_ws + FEAT_BYTES);               // 14 KB
    unsigned long long* seed0 = flags + NFLAGS;                        // 4 KB

    semiconv_kernel<<<(BATCH * HW) / (256 * 4), 256, 0, stream>>>(
        x, conv_w, conv_b, gate, rand_pixel, feat, flags, seed0);

    stick_kernel<<<BATCH * BLK_PER_B, NT, 0, stream>>>(
        feat, rand_pixel, log_sigma, masks, scopes, flags, seed0);
}